// Round 3
// baseline (87.444 us; speedup 1.0000x reference)
//
#include <hip/hip_runtime.h>
#include <stdint.h>

typedef _Float16 half8 __attribute__((ext_vector_type(8)));
typedef float floatx4 __attribute__((ext_vector_type(4)));
typedef uint32_t u32x4 __attribute__((ext_vector_type(4)));

#define BM 128
#define BN 128
#define BK 64
#define NT 512
#define KT_BASE 8      // 512/64 base-K tiles
#define KT_TOTAL 72    // 8 + 4096/64 spline-K tiles
#define IF 512
#define NF 512

__device__ __forceinline__ uint32_t swz(uint32_t b) {
  // rows are 128B; XOR byte bits [6:4] with (row&7) to kill ds_read_b128 bank conflicts
  return b ^ (((b >> 7) & 7u) << 4);
}

__device__ __forceinline__ uint32_t pk(float a, float b) {
  return __builtin_bit_cast(uint32_t, __builtin_amdgcn_cvt_pkrtz(a, b));
}

__global__ __launch_bounds__(NT, 2)
void kan_fused(const float* __restrict__ xg, const float* __restrict__ bwg,
               const float* __restrict__ swg, float* __restrict__ outg)
{
  __shared__ _Float16 As[BM * BK];
  __shared__ _Float16 Bs[BN * BK];

  const int tid = threadIdx.x;
  const int lane = tid & 63;
  const int wv = tid >> 6;     // 0..7
  const int wm = wv >> 2;      // 0..1  (64-row strip)
  const int wn = wv & 3;       // 0..3  (32-col strip)

  // XCD-aware bijective block swizzle: 256 blocks, 8 XCDs, 32/XCD contiguous
  const int bid = blockIdx.x;
  const int lb = (bid & 7) * 32 + (bid >> 3);
  const int bm0 = (lb & 63) * BM;
  const int bn0 = (lb >> 6) * BN;

  // staging decode: thread owns 2 16B chunks: rows rT and rT+64, col chunk c8
  const int rT = tid >> 3;          // 0..63
  const int c8 = (tid & 7) * 8;     // element col (fp16 elems)
  const int ii = tid & 7;           // spline: which i within the 8-i K-tile
  const uint32_t wA0 = swz((uint32_t)rT * 128u + (uint32_t)c8 * 2u);
  const uint32_t wA1 = swz((uint32_t)(rT + 64) * 128u + (uint32_t)c8 * 2u);

  char* AsB = (char*)As;
  char* BsB = (char*)Bs;

  // fragment read offsets (kk=0); kk=1 is ^64 bytes (swizzle-safe XOR, NOT add:
  // swz() can set bit6, a post-swizzle +64 would carry into the row bits)
  uint32_t rdA[4], rdB[2];
  {
    const int rr = lane & 15;
    const uint32_t cc = (uint32_t)(lane >> 4) * 16u;
#pragma unroll
    for (int mi = 0; mi < 4; ++mi)
      rdA[mi] = swz((uint32_t)(wm * 64 + mi * 16 + rr) * 128u + cc);
#pragma unroll
    for (int ni = 0; ni < 2; ++ni)
      rdB[ni] = swz((uint32_t)(wn * 32 + ni * 16 + rr) * 128u + cc);
  }

  floatx4 acc[4][2];
#pragma unroll
  for (int mi = 0; mi < 4; ++mi)
#pragma unroll
    for (int ni = 0; ni < 2; ++ni)
      acc[mi][ni] = (floatx4){0.f, 0.f, 0.f, 0.f};

  float4 aL[4];   // base-phase A fp32 staging
  float4 bL[4];   // B fp32 staging
  float xv0, xv1; // spline-phase x values

  auto LOAD = [&](int kt) {
    if (kt < KT_BASE) {
      const int kb = kt * 64;
      const float* a0 = xg + (size_t)(bm0 + rT) * IF + kb + c8;
      const float* a1 = a0 + (size_t)64 * IF;
      aL[0] = ((const float4*)a0)[0]; aL[1] = ((const float4*)a0)[1];
      aL[2] = ((const float4*)a1)[0]; aL[3] = ((const float4*)a1)[1];
      const float* b0 = bwg + (size_t)(bn0 + rT) * IF + kb + c8;
      const float* b1 = b0 + (size_t)64 * IF;
      bL[0] = ((const float4*)b0)[0]; bL[1] = ((const float4*)b0)[1];
      bL[2] = ((const float4*)b1)[0]; bL[3] = ((const float4*)b1)[1];
    } else {
      const int ks = (kt - KT_BASE) * 64;
      const int i0 = ks >> 3;
      xv0 = xg[(size_t)(bm0 + rT) * IF + i0 + ii];
      xv1 = xg[(size_t)(bm0 + rT + 64) * IF + i0 + ii];
      const float* b0 = swg + (size_t)(bn0 + rT) * 4096 + ks + c8;
      const float* b1 = b0 + (size_t)64 * 4096;
      bL[0] = ((const float4*)b0)[0]; bL[1] = ((const float4*)b0)[1];
      bL[2] = ((const float4*)b1)[0]; bL[3] = ((const float4*)b1)[1];
    }
  };

  // closed-form uniform cubic B-spline: grid = -2.2 + 0.4*t, h=0.4
  auto BASIS = [&](float xv) -> u32x4 {
    float u = (xv + 2.2f) * 2.5f;
    int j = (int)u;
    j = j < 3 ? 3 : (j > 7 ? 7 : j);
    float t = u - (float)j;
    float omt = 1.0f - t;
    float t2 = t * t, t3 = t2 * t;
    const float s6 = 0.16666666666666666f;
    float w0 = omt * omt * omt * s6;
    float w1 = (3.0f * t3 - 6.0f * t2 + 4.0f) * s6;
    float w2 = (-3.0f * t3 + 3.0f * t2 + 3.0f * t + 1.0f) * s6;
    float w3 = t3 * s6;
    uint32_t c0 = pk(w0, w1);
    uint32_t c1 = pk(w2, w3);
    const int j3 = j - 3;              // 0..4 : window start (halfword units)
    const bool odd = (j3 & 1) != 0;
    uint32_t lo  = odd ? (c0 << 16) : c0;
    uint32_t mid = odd ? ((c0 >> 16) | (c1 << 16)) : c1;
    uint32_t hi  = odd ? (c1 >> 16) : 0u;
    const int wofs = j3 >> 1;          // word offset 0..2
    u32x4 r;
    r.x = (wofs == 0) ? lo : 0u;
    r.y = (wofs == 0) ? mid : ((wofs == 1) ? lo : 0u);
    r.z = (wofs == 0) ? hi : ((wofs == 1) ? mid : lo);
    r.w = (wofs == 1) ? hi : ((wofs == 2) ? mid : 0u);
    return r;
  };

  auto WRITE = [&](int kt) {
    if (kt < KT_BASE) {
      u32x4 v0; v0.x = pk(aL[0].x, aL[0].y); v0.y = pk(aL[0].z, aL[0].w);
                v0.z = pk(aL[1].x, aL[1].y); v0.w = pk(aL[1].z, aL[1].w);
      u32x4 v1; v1.x = pk(aL[2].x, aL[2].y); v1.y = pk(aL[2].z, aL[2].w);
                v1.z = pk(aL[3].x, aL[3].y); v1.w = pk(aL[3].z, aL[3].w);
      *(u32x4*)(AsB + wA0) = v0;
      *(u32x4*)(AsB + wA1) = v1;
    } else {
      *(u32x4*)(AsB + wA0) = BASIS(xv0);
      *(u32x4*)(AsB + wA1) = BASIS(xv1);
    }
    u32x4 u0; u0.x = pk(bL[0].x, bL[0].y); u0.y = pk(bL[0].z, bL[0].w);
              u0.z = pk(bL[1].x, bL[1].y); u0.w = pk(bL[1].z, bL[1].w);
    u32x4 u1; u1.x = pk(bL[2].x, bL[2].y); u1.y = pk(bL[2].z, bL[2].w);
              u1.z = pk(bL[3].x, bL[3].y); u1.w = pk(bL[3].z, bL[3].w);
    *(u32x4*)(BsB + wA0) = u0;
    *(u32x4*)(BsB + wA1) = u1;
  };

  auto COMPUTE = [&]() {
#pragma unroll
    for (int kk = 0; kk < 2; ++kk) {
      const uint32_t ko = (uint32_t)(kk * 64);
      half8 a[4], b[2];
#pragma unroll
      for (int mi = 0; mi < 4; ++mi) {
        const uint32_t off = rdA[mi] ^ ko;   // XOR, not add (swizzle-safe)
        a[mi] = *(const half8*)(AsB + off);
      }
#pragma unroll
      for (int ni = 0; ni < 2; ++ni) {
        const uint32_t off = rdB[ni] ^ ko;
        b[ni] = *(const half8*)(BsB + off);
      }
#pragma unroll
      for (int mi = 0; mi < 4; ++mi)
#pragma unroll
        for (int ni = 0; ni < 2; ++ni)
          acc[mi][ni] = __builtin_amdgcn_mfma_f32_16x16x32_f16(a[mi], b[ni], acc[mi][ni], 0, 0, 0);
    }
  };

  LOAD(0);
  WRITE(0);
  __syncthreads();
#pragma unroll 1
  for (int kt = 0; kt < KT_TOTAL; ++kt) {
    const bool more = (kt + 1) < KT_TOTAL;
    if (more) LOAD(kt + 1);     // issue next-tile global loads before MFMA phase
    COMPUTE();
    __syncthreads();            // all LDS reads done
    if (more) WRITE(kt + 1);    // convert + ds_write next tile
    __syncthreads();
  }

  // epilogue: C/D layout col=lane&15, row=(lane>>4)*4+e (m89/m91-verified)
  const int er = (lane >> 4) * 4;
  const int ec = lane & 15;
#pragma unroll
  for (int mi = 0; mi < 4; ++mi) {
#pragma unroll
    for (int ni = 0; ni < 2; ++ni) {
      const size_t base = (size_t)(bm0 + wm * 64 + mi * 16 + er) * NF
                        + (size_t)(bn0 + wn * 32 + ni * 16 + ec);
#pragma unroll
      for (int e = 0; e < 4; ++e)
        outg[base + (size_t)e * NF] = acc[mi][ni][e];
    }
  }
}

extern "C" void kernel_launch(void* const* d_in, const int* in_sizes, int n_in,
                              void* d_out, int out_size, void* d_ws, size_t ws_size,
                              hipStream_t stream) {
  const float* x  = (const float*)d_in[0];
  const float* bw = (const float*)d_in[1];
  const float* sw = (const float*)d_in[2];
  float* out = (float*)d_out;
  hipLaunchKernelGGL(kan_fused, dim3(256), dim3(NT), 0, stream, x, bw, sw, out);
}